// Round 1
// 1002.239 us; speedup vs baseline: 1.0450x; 1.0450x over previous
//
#include <hip/hip_runtime.h>
#include <hip/hip_bf16.h>

// Problem constants
constexpr int NB  = 2;     // batch
constexpr int TT  = 2048;  // T
constexpr int MEM = 2048;  // M (xl memory length)
constexpr int CC  = 1024;  // C
constexpr int NH  = 16;    // heads
constexpr int HD  = 64;    // head dim
constexpr int TKK = 4096;  // T + M
constexpr int BT  = NB * TT;

typedef __attribute__((ext_vector_type(8))) short short8;
typedef __attribute__((ext_vector_type(4))) float floatx4;

struct __align__(8) us4 { unsigned short x, y, z, w; };

__device__ __forceinline__ unsigned short f2bf(float f) {
  union { float f; unsigned int u; } v; v.f = f;
  return (unsigned short)((v.u + 0x7fffu + ((v.u >> 16) & 1u)) >> 16);
}

// ---------------------------------------------------------------------------
// Kernel 1: xl_memory (B, M, 2, C) fp32 -> k_ws / v_ws bf16 in (B, H, TK, D)
// layout (rows 0..M-1). Rows M..TK-1 are filled by gemm_qkv.
// ---------------------------------------------------------------------------
__global__ __launch_bounds__(256) void prep_xl_k(const float* __restrict__ xl,
    unsigned short* __restrict__ k_ws, unsigned short* __restrict__ v_ws) {
  int idx = blockIdx.x * 256 + threadIdx.x;  // over NB*MEM*CC/4 = 1048576
  int c   = (idx & 255) << 2;                // CC/4 = 256 groups of 4
  int rem = idx >> 8;
  int m   = rem & 2047;
  int b   = rem >> 11;
  size_t src = ((size_t)(b * MEM + m)) * 2 * CC + c;
  float4 kk = *(const float4*)&xl[src];
  float4 vv = *(const float4*)&xl[src + CC];
  int h = c >> 6, d = c & 63;
  size_t dst = ((size_t)((b * NH + h) * TKK) + m) * HD + d;
  *(us4*)&k_ws[dst] = us4{f2bf(kk.x), f2bf(kk.y), f2bf(kk.z), f2bf(kk.w)};
  *(us4*)&v_ws[dst] = us4{f2bf(vv.x), f2bf(vv.y), f2bf(vv.z), f2bf(vv.w)};
}

// ---------------------------------------------------------------------------
// Kernel 2: QKV projection. A = x (4096x1024 fp32), B = [Wq|Wk|Wv].
// 128x128 tile, BK=32, 4 waves each 64x64 (4x4 of 16x16x32 bf16 MFMA).
// Epilogue scatters to head-layout bf16 ws; k/v also go to new_xl (fp32 out).
// ---------------------------------------------------------------------------
__global__ __launch_bounds__(256) void gemm_qkv_k(
    const float* __restrict__ x, const float* __restrict__ Wq,
    const float* __restrict__ Wk, const float* __restrict__ Wv,
    unsigned short* __restrict__ q_ws, unsigned short* __restrict__ k_ws,
    unsigned short* __restrict__ v_ws, float* __restrict__ out_xl) {
  __shared__ unsigned short As[128][32];  // [m][k]
  __shared__ unsigned short Bs[128][40];  // transposed [n][k], pad 8 -> 16B-aligned rows
  const int tid = threadIdx.x;
  const int m0 = blockIdx.x * 128;
  const int nb = blockIdx.y;  // 0..23 over 3072 cols
  const float* __restrict__ Wsrc = (nb < 8) ? Wq : ((nb < 16) ? Wk : Wv);
  const int n0 = (nb & 7) * 128;
  const int wave = tid >> 6, lane = tid & 63;
  const int mh = (wave >> 1) * 64, nh = (wave & 1) * 64;
  const int ln = lane & 15, qd = lane >> 4;
  const floatx4 fzero = {0.f, 0.f, 0.f, 0.f};

  floatx4 acc[4][4];
#pragma unroll
  for (int i = 0; i < 4; i++)
#pragma unroll
    for (int j = 0; j < 4; j++) acc[i][j] = fzero;

  for (int kt = 0; kt < CC; kt += 32) {
    __syncthreads();
    // stage A: 128x32 fp32 -> bf16, coalesced float4
#pragma unroll
    for (int i = 0; i < 4; i++) {
      int e = tid + i * 256;
      int row = e >> 3, kc = (e & 7) << 2;
      float4 a4 = *(const float4*)&x[(size_t)(m0 + row) * CC + kt + kc];
      *(us4*)&As[row][kc] = us4{f2bf(a4.x), f2bf(a4.y), f2bf(a4.z), f2bf(a4.w)};
    }
    // stage B transposed: each thread reads 4 k-rows at one n (coalesced dwords),
    // writes one contiguous b64 to Bs[n][4k..]
#pragma unroll
    for (int i = 0; i < 4; i++) {
      int e = tid + i * 256;
      int n = e & 127, kg = e >> 7;
      const float* p = &Wsrc[(size_t)(kt + kg * 4) * CC + n0 + n];
      float b0 = p[0], b1 = p[CC], b2 = p[2 * CC], b3 = p[3 * CC];
      *(us4*)&Bs[n][kg * 4] = us4{f2bf(b0), f2bf(b1), f2bf(b2), f2bf(b3)};
    }
    __syncthreads();
    short8 af[4], bfr[4];
#pragma unroll
    for (int mf = 0; mf < 4; mf++) af[mf]  = *(const short8*)&As[mh + mf * 16 + ln][qd * 8];
#pragma unroll
    for (int nf = 0; nf < 4; nf++) bfr[nf] = *(const short8*)&Bs[nh + nf * 16 + ln][qd * 8];
#pragma unroll
    for (int mf = 0; mf < 4; mf++)
#pragma unroll
      for (int nf = 0; nf < 4; nf++)
        acc[mf][nf] = __builtin_amdgcn_mfma_f32_16x16x32_bf16(af[mf], bfr[nf], acc[mf][nf], 0, 0, 0);
  }

  const int sel = nb >> 3;  // 0=q 1=k 2=v
#pragma unroll
  for (int mf = 0; mf < 4; mf++) {
#pragma unroll
    for (int nf = 0; nf < 4; nf++) {
      int gn = n0 + nh + nf * 16 + ln;  // 0..1023 within matrix
      int h = gn >> 6, d = gn & 63;
#pragma unroll
      for (int r = 0; r < 4; r++) {
        int gm = m0 + mh + mf * 16 + qd * 4 + r;  // C/D layout: row = quad*4+reg
        int b = gm >> 11, t = gm & 2047;
        float val = acc[mf][nf][r];
        unsigned short bv = f2bf(val);
        if (sel == 0) {
          q_ws[((size_t)((b * NH + h) * TT) + t) * HD + d] = bv;
        } else if (sel == 1) {
          k_ws[((size_t)((b * NH + h) * TKK) + MEM + t) * HD + d] = bv;
          out_xl[(((size_t)(b * TT + t)) * 2 + 0) * CC + gn] = val;
        } else {
          v_ws[((size_t)((b * NH + h) * TKK) + MEM + t) * HD + d] = bv;
          out_xl[(((size_t)(b * TT + t)) * 2 + 1) * CC + gn] = val;
        }
      }
    }
  }
}

// ---------------------------------------------------------------------------
// Kernel 3: flash attention. One block per (q-tile of 64 rows, head, batch).
// Batch is the FASTEST grid bit so the (b=0,b=1) pair at the same (qt,h) is
// co-resident and the rel-pos bias (537 MB) second read hits L2/L3.
// qt runs DESCENDING across the dispatch order: long blocks (ntiles=qt+33)
// launch first, short ones fill the tail -> no ragged finish.
// LDS 25.6 KB/block -> up to 6 blocks/CU (was 43 KB -> 3, grid-limited to 2).
// 4 waves x 16 q-rows. S = Q.K^T via 16x16x32 MFMA; online softmax per row;
// P -> per-wave LDS (swizzled) -> A-frag; O += P.V with V XOR-swizzle-transposed.
// ---------------------------------------------------------------------------
__global__ __launch_bounds__(256) void attn_k(
    const unsigned short* __restrict__ q_ws, const unsigned short* __restrict__ k_ws,
    const unsigned short* __restrict__ v_ws, const float* __restrict__ rel,
    unsigned short* __restrict__ wv_ws) {
  __shared__ unsigned short Ks[64][72];  // natural [kcol][dim], pad 8
  __shared__ unsigned short Vs[64][64];  // transposed [dim][krow], XOR-swizzled 8-elem groups
  __shared__ unsigned short Ps[4][16][64];   // per-wave P scratch, same swizzle
  const int idx = blockIdx.x;       // 0..1023
  const int qt = 31 - (idx >> 5);   // descending work order
  const int h  = (idx >> 1) & 15;
  const int b  = idx & 1;
  const int tid = threadIdx.x;
  const int wave = tid >> 6, lane = tid & 63;
  const int ln = lane & 15, qd = lane >> 4;
  const int q0 = qt * 64;
  const int qrow_w = q0 + wave * 16;
  const floatx4 fzero = {0.f, 0.f, 0.f, 0.f};

  // Q A-frags: lane holds Q[m=ln][qd*8..+8 (+32*ks)]
  short8 qf[2];
#pragma unroll
  for (int ks = 0; ks < 2; ks++)
    qf[ks] = *(const short8*)&q_ws[((size_t)((b * NH + h) * TT) + qrow_w + ln) * HD + ks * 32 + qd * 8];

  floatx4 of[4];
  float mrow[4], lrow[4];
#pragma unroll
  for (int nf = 0; nf < 4; nf++) of[nf] = fzero;
#pragma unroll
  for (int r = 0; r < 4; r++) { mrow[r] = -1e30f; lrow[r] = 0.f; }

  const int ntiles = qt + 33;  // valid k-tiles: cols <= q0+63+2048
  for (int kt = 0; kt < ntiles; kt++) {
    const int kbase = kt * 64;
    __syncthreads();
    // stage K (natural) and V (swizzled transpose) for this batch
    {
      const size_t rowbase = (size_t)((b * NH + h) * TKK) + kbase;
#pragma unroll
      for (int i = 0; i < 2; i++) {
        int e = tid + i * 256;
        int r = e >> 3, c0 = (e & 7) << 3;
        *(short8*)&Ks[r][c0] = *(const short8*)&k_ws[(rowbase + r) * HD + c0];
        short8 v8 = *(const short8*)&v_ws[(rowbase + r) * HD + c0];
#pragma unroll
        for (int j = 0; j < 8; j++) {
          int d = c0 + j;
          int slot = ((r >> 3) ^ (d & 7) ^ (d >> 3)) & 7;
          Vs[d][(slot << 3) | (r & 7)] = (unsigned short)v8[j];
        }
      }
    }
    __syncthreads();

    // bias (paired b=0/b=1 blocks read the same rows ~concurrently -> L2/L3 hit)
    float bias[4][4];
#pragma unroll
    for (int nf = 0; nf < 4; nf++)
#pragma unroll
      for (int r = 0; r < 4; r++)
        bias[nf][r] = rel[((size_t)(h * TT) + qrow_w + qd * 4 + r) * TKK + kbase + nf * 16 + ln];

    const bool lastTile = (kt == ntiles - 1);

    floatx4 sacc[4];
#pragma unroll
    for (int nf = 0; nf < 4; nf++) sacc[nf] = fzero;
#pragma unroll
    for (int ks = 0; ks < 2; ks++)
#pragma unroll
      for (int nf = 0; nf < 4; nf++) {
        short8 kf = *(const short8*)&Ks[nf * 16 + ln][ks * 32 + qd * 8];
        sacc[nf] = __builtin_amdgcn_mfma_f32_16x16x32_bf16(qf[ks], kf, sacc[nf], 0, 0, 0);
      }

    float sv[4][4];
#pragma unroll
    for (int nf = 0; nf < 4; nf++)
#pragma unroll
      for (int r = 0; r < 4; r++)
        sv[nf][r] = (sacc[nf][r] + bias[nf][r]) * 0.125f;  // (qk + rel) * d^-0.5
    if (lastTile) {
#pragma unroll
      for (int nf = 0; nf < 4; nf++)
#pragma unroll
        for (int r = 0; r < 4; r++) {
          int kcol = kbase + nf * 16 + ln;
          int qrow = qrow_w + qd * 4 + r;
          if (kcol > qrow + MEM) sv[nf][r] = -1e30f;
        }
    }

    // online softmax per row (rows live in (qd, r); cols across 16 lanes of quad)
#pragma unroll
    for (int r = 0; r < 4; r++) {
      float mx = fmaxf(fmaxf(sv[0][r], sv[1][r]), fmaxf(sv[2][r], sv[3][r]));
#pragma unroll
      for (int off = 8; off >= 1; off >>= 1)
        mx = fmaxf(mx, __shfl_xor(mx, off, 64));
      float mnew = fmaxf(mrow[r], mx);
      float alpha = __expf(mrow[r] - mnew);
      mrow[r] = mnew;
      float sum = 0.f;
#pragma unroll
      for (int nf = 0; nf < 4; nf++) {
        float p = __expf(sv[nf][r] - mnew);
        sv[nf][r] = p;
        sum += p;
      }
#pragma unroll
      for (int off = 8; off >= 1; off >>= 1)
        sum += __shfl_xor(sum, off, 64);
      lrow[r] = lrow[r] * alpha + sum;
#pragma unroll
      for (int nf = 0; nf < 4; nf++) of[nf][r] *= alpha;
    }

    // P: C-layout -> LDS (swizzled) -> A-layout (per-wave private, no barrier)
#pragma unroll
    for (int nf = 0; nf < 4; nf++)
#pragma unroll
      for (int r = 0; r < 4; r++) {
        int row = qd * 4 + r;
        int col = nf * 16 + ln;
        int slot = ((col >> 3) ^ (row & 7) ^ (row >> 3)) & 7;
        Ps[wave][row][(slot << 3) | (col & 7)] = f2bf(sv[nf][r]);
      }

#pragma unroll
    for (int ks = 0; ks < 2; ks++) {
      int g = qd + 4 * ks;
      int pslot = (g ^ (ln & 7) ^ (ln >> 3)) & 7;
      short8 pf = *(const short8*)&Ps[wave][ln][pslot << 3];
#pragma unroll
      for (int nf = 0; nf < 4; nf++) {
        int dd = nf * 16 + ln;
        int vslot = (g ^ (dd & 7) ^ (dd >> 3)) & 7;
        short8 vf = *(const short8*)&Vs[dd][vslot << 3];
        of[nf] = __builtin_amdgcn_mfma_f32_16x16x32_bf16(pf, vf, of[nf], 0, 0, 0);
      }
    }
  }

  // normalize + store wv (bf16) in (B*T, C) for the out-proj GEMM
  {
    float inv[4];
#pragma unroll
    for (int r = 0; r < 4; r++) inv[r] = 1.f / lrow[r];
#pragma unroll
    for (int nf = 0; nf < 4; nf++)
#pragma unroll
      for (int r = 0; r < 4; r++)
        wv_ws[((size_t)(b * TT) + qrow_w + qd * 4 + r) * CC + h * 64 + nf * 16 + ln] =
            f2bf(of[nf][r] * inv[r]);
  }
}

// ---------------------------------------------------------------------------
// Kernel 4: out = wv @ Wp + bp   (A bf16 ws, B fp32 -> bf16, out fp32)
// ---------------------------------------------------------------------------
__global__ __launch_bounds__(256) void gemm_out_k(
    const unsigned short* __restrict__ a_bf, const float* __restrict__ Wp,
    const float* __restrict__ bp, float* __restrict__ out) {
  __shared__ unsigned short As[128][32];
  __shared__ unsigned short Bs[128][40];
  const int tid = threadIdx.x;
  const int m0 = blockIdx.x * 128;
  const int n0 = blockIdx.y * 128;
  const int wave = tid >> 6, lane = tid & 63;
  const int mh = (wave >> 1) * 64, nh = (wave & 1) * 64;
  const int ln = lane & 15, qd = lane >> 4;
  const floatx4 fzero = {0.f, 0.f, 0.f, 0.f};

  floatx4 acc[4][4];
#pragma unroll
  for (int i = 0; i < 4; i++)
#pragma unroll
    for (int j = 0; j < 4; j++) acc[i][j] = fzero;

  for (int kt = 0; kt < CC; kt += 32) {
    __syncthreads();
#pragma unroll
    for (int i = 0; i < 2; i++) {  // A already bf16: b128 copies
      int e = tid + i * 256;
      int row = e >> 2, c0 = (e & 3) << 3;
      *(short8*)&As[row][c0] = *(const short8*)&a_bf[(size_t)(m0 + row) * CC + kt + c0];
    }
#pragma unroll
    for (int i = 0; i < 4; i++) {
      int e = tid + i * 256;
      int n = e & 127, kg = e >> 7;
      const float* p = &Wp[(size_t)(kt + kg * 4) * CC + n0 + n];
      float b0 = p[0], b1 = p[CC], b2 = p[2 * CC], b3 = p[3 * CC];
      *(us4*)&Bs[n][kg * 4] = us4{f2bf(b0), f2bf(b1), f2bf(b2), f2bf(b3)};
    }
    __syncthreads();
    short8 af[4], bfr[4];
#pragma unroll
    for (int mf = 0; mf < 4; mf++) af[mf]  = *(const short8*)&As[mh + mf * 16 + ln][qd * 8];
#pragma unroll
    for (int nf = 0; nf < 4; nf++) bfr[nf] = *(const short8*)&Bs[nh + nf * 16 + ln][qd * 8];
#pragma unroll
    for (int mf = 0; mf < 4; mf++)
#pragma unroll
      for (int nf = 0; nf < 4; nf++)
        acc[mf][nf] = __builtin_amdgcn_mfma_f32_16x16x32_bf16(af[mf], bfr[nf], acc[mf][nf], 0, 0, 0);
  }

#pragma unroll
  for (int mf = 0; mf < 4; mf++)
#pragma unroll
    for (int nf = 0; nf < 4; nf++) {
      int gn = n0 + nh + nf * 16 + ln;
      float bias = bp[gn];
#pragma unroll
      for (int r = 0; r < 4; r++) {
        int gm = m0 + mh + mf * 16 + qd * 4 + r;
        out[(size_t)gm * CC + gn] = acc[mf][nf][r] + bias;
      }
    }
}

// ---------------------------------------------------------------------------
// Workspace map (48 MB total):
//   [ 0,  8M)  q_ws  bf16 (B,H,T,D)
//   [ 8, 24M)  k_ws  bf16 (B,H,TK,D)
//   [24, 40M)  v_ws  bf16 (B,H,TK,D)
//   [40, 48M)  wv_ws bf16 (B*T, C)
// ---------------------------------------------------------------------------
extern "C" void kernel_launch(void* const* d_in, const int* in_sizes, int n_in,
                              void* d_out, int out_size, void* d_ws, size_t ws_size,
                              hipStream_t stream) {
  const float* rel = (const float*)d_in[0];
  const float* x   = (const float*)d_in[1];
  const float* xl  = (const float*)d_in[2];
  const float* Wq  = (const float*)d_in[3];
  const float* Wk  = (const float*)d_in[4];
  const float* Wv  = (const float*)d_in[5];
  const float* Wp  = (const float*)d_in[6];
  const float* bp  = (const float*)d_in[7];
  float* out    = (float*)d_out;
  float* out_xl = out + (size_t)BT * CC;  // new_xl_memory (B,T,2,C)

  char* ws = (char*)d_ws;
  unsigned short* q_ws  = (unsigned short*)(ws);
  unsigned short* k_ws  = (unsigned short*)(ws + (size_t)(8)  * 1024 * 1024);
  unsigned short* v_ws  = (unsigned short*)(ws + (size_t)(24) * 1024 * 1024);
  unsigned short* wv_ws = (unsigned short*)(ws + (size_t)(40) * 1024 * 1024);

  prep_xl_k<<<dim3(4096), dim3(256), 0, stream>>>(xl, k_ws, v_ws);
  gemm_qkv_k<<<dim3(32, 24), dim3(256), 0, stream>>>(x, Wq, Wk, Wv, q_ws, k_ws, v_ws, out_xl);
  attn_k<<<dim3(1024), dim3(256), 0, stream>>>(q_ws, k_ws, v_ws, rel, wv_ws);
  gemm_out_k<<<dim3(32, 8), dim3(256), 0, stream>>>(wv_ws, Wp, bp, out);
}

// Round 2
// 992.530 us; speedup vs baseline: 1.0553x; 1.0098x over previous
//
#include <hip/hip_runtime.h>
#include <hip/hip_bf16.h>

// Problem constants
constexpr int NB  = 2;     // batch
constexpr int TT  = 2048;  // T
constexpr int MEM = 2048;  // M (xl memory length)
constexpr int CC  = 1024;  // C
constexpr int NH  = 16;    // heads
constexpr int HD  = 64;    // head dim
constexpr int TKK = 4096;  // T + M
constexpr int BT  = NB * TT;

typedef __attribute__((ext_vector_type(8))) short short8;
typedef __attribute__((ext_vector_type(4))) float floatx4;

struct __align__(8) us4 { unsigned short x, y, z, w; };

__device__ __forceinline__ unsigned short f2bf(float f) {
  union { float f; unsigned int u; } v; v.f = f;
  return (unsigned short)((v.u + 0x7fffu + ((v.u >> 16) & 1u)) >> 16);
}

// ---------------------------------------------------------------------------
// Kernel 1: xl_memory (B, M, 2, C) fp32 -> k_ws / v_ws bf16 in (B, H, TK, D)
// layout (rows 0..M-1). Rows M..TK-1 are filled by gemm_qkv.
// ---------------------------------------------------------------------------
__global__ __launch_bounds__(256) void prep_xl_k(const float* __restrict__ xl,
    unsigned short* __restrict__ k_ws, unsigned short* __restrict__ v_ws) {
  int idx = blockIdx.x * 256 + threadIdx.x;  // over NB*MEM*CC/4 = 1048576
  int c   = (idx & 255) << 2;                // CC/4 = 256 groups of 4
  int rem = idx >> 8;
  int m   = rem & 2047;
  int b   = rem >> 11;
  size_t src = ((size_t)(b * MEM + m)) * 2 * CC + c;
  float4 kk = *(const float4*)&xl[src];
  float4 vv = *(const float4*)&xl[src + CC];
  int h = c >> 6, d = c & 63;
  size_t dst = ((size_t)((b * NH + h) * TKK) + m) * HD + d;
  *(us4*)&k_ws[dst] = us4{f2bf(kk.x), f2bf(kk.y), f2bf(kk.z), f2bf(kk.w)};
  *(us4*)&v_ws[dst] = us4{f2bf(vv.x), f2bf(vv.y), f2bf(vv.z), f2bf(vv.w)};
}

// ---------------------------------------------------------------------------
// Kernel 2: QKV projection. A = x (4096x1024 fp32), B = [Wq|Wk|Wv].
// 128x128 tile, BK=32, 4 waves each 64x64 (4x4 of 16x16x32 bf16 MFMA).
// Epilogue scatters to head-layout bf16 ws; k/v also go to new_xl (fp32 out).
// ---------------------------------------------------------------------------
__global__ __launch_bounds__(256) void gemm_qkv_k(
    const float* __restrict__ x, const float* __restrict__ Wq,
    const float* __restrict__ Wk, const float* __restrict__ Wv,
    unsigned short* __restrict__ q_ws, unsigned short* __restrict__ k_ws,
    unsigned short* __restrict__ v_ws, float* __restrict__ out_xl) {
  __shared__ unsigned short As[128][32];  // [m][k]
  __shared__ unsigned short Bs[128][40];  // transposed [n][k], pad 8 -> 16B-aligned rows
  const int tid = threadIdx.x;
  const int m0 = blockIdx.x * 128;
  const int nb = blockIdx.y;  // 0..23 over 3072 cols
  const float* __restrict__ Wsrc = (nb < 8) ? Wq : ((nb < 16) ? Wk : Wv);
  const int n0 = (nb & 7) * 128;
  const int wave = tid >> 6, lane = tid & 63;
  const int mh = (wave >> 1) * 64, nh = (wave & 1) * 64;
  const int ln = lane & 15, qd = lane >> 4;
  const floatx4 fzero = {0.f, 0.f, 0.f, 0.f};

  floatx4 acc[4][4];
#pragma unroll
  for (int i = 0; i < 4; i++)
#pragma unroll
    for (int j = 0; j < 4; j++) acc[i][j] = fzero;

  for (int kt = 0; kt < CC; kt += 32) {
    __syncthreads();
    // stage A: 128x32 fp32 -> bf16, coalesced float4
#pragma unroll
    for (int i = 0; i < 4; i++) {
      int e = tid + i * 256;
      int row = e >> 3, kc = (e & 7) << 2;
      float4 a4 = *(const float4*)&x[(size_t)(m0 + row) * CC + kt + kc];
      *(us4*)&As[row][kc] = us4{f2bf(a4.x), f2bf(a4.y), f2bf(a4.z), f2bf(a4.w)};
    }
    // stage B transposed: each thread reads 4 k-rows at one n (coalesced dwords),
    // writes one contiguous b64 to Bs[n][4k..]
#pragma unroll
    for (int i = 0; i < 4; i++) {
      int e = tid + i * 256;
      int n = e & 127, kg = e >> 7;
      const float* p = &Wsrc[(size_t)(kt + kg * 4) * CC + n0 + n];
      float b0 = p[0], b1 = p[CC], b2 = p[2 * CC], b3 = p[3 * CC];
      *(us4*)&Bs[n][kg * 4] = us4{f2bf(b0), f2bf(b1), f2bf(b2), f2bf(b3)};
    }
    __syncthreads();
    short8 af[4], bfr[4];
#pragma unroll
    for (int mf = 0; mf < 4; mf++) af[mf]  = *(const short8*)&As[mh + mf * 16 + ln][qd * 8];
#pragma unroll
    for (int nf = 0; nf < 4; nf++) bfr[nf] = *(const short8*)&Bs[nh + nf * 16 + ln][qd * 8];
#pragma unroll
    for (int mf = 0; mf < 4; mf++)
#pragma unroll
      for (int nf = 0; nf < 4; nf++)
        acc[mf][nf] = __builtin_amdgcn_mfma_f32_16x16x32_bf16(af[mf], bfr[nf], acc[mf][nf], 0, 0, 0);
  }

  const int sel = nb >> 3;  // 0=q 1=k 2=v
#pragma unroll
  for (int mf = 0; mf < 4; mf++) {
#pragma unroll
    for (int nf = 0; nf < 4; nf++) {
      int gn = n0 + nh + nf * 16 + ln;  // 0..1023 within matrix
      int h = gn >> 6, d = gn & 63;
#pragma unroll
      for (int r = 0; r < 4; r++) {
        int gm = m0 + mh + mf * 16 + qd * 4 + r;  // C/D layout: row = quad*4+reg
        int b = gm >> 11, t = gm & 2047;
        float val = acc[mf][nf][r];
        unsigned short bv = f2bf(val);
        if (sel == 0) {
          q_ws[((size_t)((b * NH + h) * TT) + t) * HD + d] = bv;
        } else if (sel == 1) {
          k_ws[((size_t)((b * NH + h) * TKK) + MEM + t) * HD + d] = bv;
          out_xl[(((size_t)(b * TT + t)) * 2 + 0) * CC + gn] = val;
        } else {
          v_ws[((size_t)((b * NH + h) * TKK) + MEM + t) * HD + d] = bv;
          out_xl[(((size_t)(b * TT + t)) * 2 + 1) * CC + gn] = val;
        }
      }
    }
  }
}

// ---------------------------------------------------------------------------
// Kernel 3: flash attention. One block per (q-tile of 64 rows, head, batch).
// Batch fastest grid bit (bias L2/L3 pairing); qt descending (long blocks 1st).
// NEW this round:
//  - double-buffered K/V tiles, ONE barrier per k-tile (was 2)
//  - async reg-staging: tile t+1 global loads issued before tile t's compute,
//    LDS writes after compute (HBM/L2 latency hidden under MFMA+softmax)
//  - bias prefetched one tile ahead into registers
//  - V staged via coalesced column loads -> 2x ds_write_b128 (replaces
//    16x ds_write_b16 scatter + per-element extraction VALU)
// LDS 45 KB -> 3 blocks/CU (12 waves/CU), latency now prefetch-hidden.
// ---------------------------------------------------------------------------
__global__ __launch_bounds__(256) void attn_k(
    const unsigned short* __restrict__ q_ws, const unsigned short* __restrict__ k_ws,
    const unsigned short* __restrict__ v_ws, const float* __restrict__ rel,
    unsigned short* __restrict__ wv_ws) {
  __shared__ unsigned short Ks[2][64][72];  // natural [kcol][dim], pad 8
  __shared__ unsigned short Vs[2][64][72];  // transposed [dim][krow], XOR-swizzled 8-elem groups, pad 8
  __shared__ unsigned short Ps[4][16][72];  // per-wave P scratch, same swizzle, pad 8
  const int idx = blockIdx.x;       // 0..1023
  const int qt = 31 - (idx >> 5);   // descending work order
  const int h  = (idx >> 1) & 15;
  const int b  = idx & 1;
  const int tid = threadIdx.x;
  const int wave = tid >> 6, lane = tid & 63;
  const int ln = lane & 15, qd = lane >> 4;
  const int q0 = qt * 64;
  const int qrow_w = q0 + wave * 16;
  const floatx4 fzero = {0.f, 0.f, 0.f, 0.f};

  // staging roles
  const int kr0 = tid >> 3;            // 0..31 (second b128 covers +32)
  const int kc0 = (tid & 7) << 3;      // 0..56
  const int vd  = tid & 63;            // V column (d)
  const int vkg = tid >> 6;            // V k-group of 16
  const size_t khbase = (size_t)((b * NH + h) * TKK);

  // Q A-frags: lane holds Q[m=ln][qd*8..+8 (+32*ks)]
  short8 qf[2];
#pragma unroll
  for (int ks = 0; ks < 2; ks++)
    qf[ks] = *(const short8*)&q_ws[((size_t)((b * NH + h) * TT) + qrow_w + ln) * HD + ks * 32 + qd * 8];

  // bias row bases (4 rows per thread)
  const float* biasrow[4];
#pragma unroll
  for (int r = 0; r < 4; r++)
    biasrow[r] = &rel[((size_t)(h * TT) + qrow_w + qd * 4 + r) * TKK + ln];

  floatx4 of[4];
  float mrow[4], lrow[4];
#pragma unroll
  for (int nf = 0; nf < 4; nf++) of[nf] = fzero;
#pragma unroll
  for (int r = 0; r < 4; r++) { mrow[r] = -1e30f; lrow[r] = 0.f; }

  const int ntiles = qt + 33;  // valid k-tiles: cols <= q0+63+2048

  // ---- prologue: stage tile 0 into buffer 0 ----
  float bcur[16];
  {
    short8 k0 = *(const short8*)&k_ws[(khbase + kr0) * HD + kc0];
    short8 k1 = *(const short8*)&k_ws[(khbase + kr0 + 32) * HD + kc0];
    ushort2 vv[8];
    const unsigned short* vp = &v_ws[(khbase + vkg * 16) * HD + vd];
#pragma unroll
    for (int j = 0; j < 8; j++) {
      vv[j].x = vp[(2 * j) * HD];
      vv[j].y = vp[(2 * j + 1) * HD];
    }
#pragma unroll
    for (int nf = 0; nf < 4; nf++)
#pragma unroll
      for (int r = 0; r < 4; r++)
        bcur[nf * 4 + r] = biasrow[r][nf * 16];
    *(short8*)&Ks[0][kr0][kc0] = k0;
    *(short8*)&Ks[0][kr0 + 32][kc0] = k1;
#pragma unroll
    for (int jj = 0; jj < 2; jj++) {
      int slot = ((vkg * 2 + jj) ^ (vd & 7) ^ (vd >> 3)) & 7;
      short8 w;
#pragma unroll
      for (int t = 0; t < 4; t++) {
        w[2 * t]     = (short)vv[jj * 4 + t].x;
        w[2 * t + 1] = (short)vv[jj * 4 + t].y;
      }
      *(short8*)&Vs[0][vd][slot << 3] = w;
    }
  }
  __syncthreads();

  int c = 0;
  for (int kt = 0; kt < ntiles; kt++) {
    const int kbase = kt * 64;
    const bool more = (kt + 1 < ntiles);

    // ---- issue prefetch for tile kt+1 (loads only; writes after compute) ----
    short8 nk0, nk1;
    ushort2 nvv[8];
    float bnx[16];
    if (more) {
      const size_t rb = khbase + kbase + 64;
      nk0 = *(const short8*)&k_ws[(rb + kr0) * HD + kc0];
      nk1 = *(const short8*)&k_ws[(rb + kr0 + 32) * HD + kc0];
      const unsigned short* vp = &v_ws[(rb + vkg * 16) * HD + vd];
#pragma unroll
      for (int j = 0; j < 8; j++) {
        nvv[j].x = vp[(2 * j) * HD];
        nvv[j].y = vp[(2 * j + 1) * HD];
      }
#pragma unroll
      for (int nf = 0; nf < 4; nf++)
#pragma unroll
        for (int r = 0; r < 4; r++)
          bnx[nf * 4 + r] = biasrow[r][kbase + 64 + nf * 16];
    }

    // ---- compute on buffer c ----
    floatx4 sacc[4];
#pragma unroll
    for (int nf = 0; nf < 4; nf++) sacc[nf] = fzero;
#pragma unroll
    for (int ks = 0; ks < 2; ks++)
#pragma unroll
      for (int nf = 0; nf < 4; nf++) {
        short8 kf = *(const short8*)&Ks[c][nf * 16 + ln][ks * 32 + qd * 8];
        sacc[nf] = __builtin_amdgcn_mfma_f32_16x16x32_bf16(qf[ks], kf, sacc[nf], 0, 0, 0);
      }

    float sv[4][4];
#pragma unroll
    for (int nf = 0; nf < 4; nf++)
#pragma unroll
      for (int r = 0; r < 4; r++)
        sv[nf][r] = (sacc[nf][r] + bcur[nf * 4 + r]) * 0.125f;  // (qk + rel) * d^-0.5
    if (kt == ntiles - 1) {
#pragma unroll
      for (int nf = 0; nf < 4; nf++)
#pragma unroll
        for (int r = 0; r < 4; r++) {
          int kcol = kbase + nf * 16 + ln;
          int qrow = qrow_w + qd * 4 + r;
          if (kcol > qrow + MEM) sv[nf][r] = -1e30f;
        }
    }

    // online softmax per row (rows live in (qd, r); cols across 16 lanes of quad)
#pragma unroll
    for (int r = 0; r < 4; r++) {
      float mx = fmaxf(fmaxf(sv[0][r], sv[1][r]), fmaxf(sv[2][r], sv[3][r]));
#pragma unroll
      for (int off = 8; off >= 1; off >>= 1)
        mx = fmaxf(mx, __shfl_xor(mx, off, 64));
      float mnew = fmaxf(mrow[r], mx);
      float alpha = __expf(mrow[r] - mnew);
      mrow[r] = mnew;
      float sum = 0.f;
#pragma unroll
      for (int nf = 0; nf < 4; nf++) {
        float p = __expf(sv[nf][r] - mnew);
        sv[nf][r] = p;
        sum += p;
      }
#pragma unroll
      for (int off = 8; off >= 1; off >>= 1)
        sum += __shfl_xor(sum, off, 64);
      lrow[r] = lrow[r] * alpha + sum;
#pragma unroll
      for (int nf = 0; nf < 4; nf++) of[nf][r] *= alpha;
    }

    // P: C-layout -> LDS (swizzled) -> A-layout (per-wave private, no barrier)
#pragma unroll
    for (int nf = 0; nf < 4; nf++)
#pragma unroll
      for (int r = 0; r < 4; r++) {
        int row = qd * 4 + r;
        int col = nf * 16 + ln;
        int slot = ((col >> 3) ^ (row & 7) ^ (row >> 3)) & 7;
        Ps[wave][row][(slot << 3) | (col & 7)] = f2bf(sv[nf][r]);
      }

#pragma unroll
    for (int ks = 0; ks < 2; ks++) {
      int g = qd + 4 * ks;
      int pslot = (g ^ (ln & 7) ^ (ln >> 3)) & 7;
      short8 pf = *(const short8*)&Ps[wave][ln][pslot << 3];
#pragma unroll
      for (int nf = 0; nf < 4; nf++) {
        int dd = nf * 16 + ln;
        int vslot = (g ^ (dd & 7) ^ (dd >> 3)) & 7;
        short8 vf = *(const short8*)&Vs[c][dd][vslot << 3];
        of[nf] = __builtin_amdgcn_mfma_f32_16x16x32_bf16(pf, vf, of[nf], 0, 0, 0);
      }
    }

    // ---- write prefetched tile into the other buffer, then single barrier ----
    if (more) {
      *(short8*)&Ks[c ^ 1][kr0][kc0] = nk0;
      *(short8*)&Ks[c ^ 1][kr0 + 32][kc0] = nk1;
#pragma unroll
      for (int jj = 0; jj < 2; jj++) {
        int slot = ((vkg * 2 + jj) ^ (vd & 7) ^ (vd >> 3)) & 7;
        short8 w;
#pragma unroll
        for (int t = 0; t < 4; t++) {
          w[2 * t]     = (short)nvv[jj * 4 + t].x;
          w[2 * t + 1] = (short)nvv[jj * 4 + t].y;
        }
        *(short8*)&Vs[c ^ 1][vd][slot << 3] = w;
      }
#pragma unroll
      for (int i = 0; i < 16; i++) bcur[i] = bnx[i];
    }
    __syncthreads();
    c ^= 1;
  }

  // normalize + store wv (bf16) in (B*T, C) for the out-proj GEMM
  {
    float inv[4];
#pragma unroll
    for (int r = 0; r < 4; r++) inv[r] = 1.f / lrow[r];
#pragma unroll
    for (int nf = 0; nf < 4; nf++)
#pragma unroll
      for (int r = 0; r < 4; r++)
        wv_ws[((size_t)(b * TT) + qrow_w + qd * 4 + r) * CC + h * 64 + nf * 16 + ln] =
            f2bf(of[nf][r] * inv[r]);
  }
}

// ---------------------------------------------------------------------------
// Kernel 4: out = wv @ Wp + bp   (A bf16 ws, B fp32 -> bf16, out fp32)
// ---------------------------------------------------------------------------
__global__ __launch_bounds__(256) void gemm_out_k(
    const unsigned short* __restrict__ a_bf, const float* __restrict__ Wp,
    const float* __restrict__ bp, float* __restrict__ out) {
  __shared__ unsigned short As[128][32];
  __shared__ unsigned short Bs[128][40];
  const int tid = threadIdx.x;
  const int m0 = blockIdx.x * 128;
  const int n0 = blockIdx.y * 128;
  const int wave = tid >> 6, lane = tid & 63;
  const int mh = (wave >> 1) * 64, nh = (wave & 1) * 64;
  const int ln = lane & 15, qd = lane >> 4;
  const floatx4 fzero = {0.f, 0.f, 0.f, 0.f};

  floatx4 acc[4][4];
#pragma unroll
  for (int i = 0; i < 4; i++)
#pragma unroll
    for (int j = 0; j < 4; j++) acc[i][j] = fzero;

  for (int kt = 0; kt < CC; kt += 32) {
    __syncthreads();
#pragma unroll
    for (int i = 0; i < 2; i++) {  // A already bf16: b128 copies
      int e = tid + i * 256;
      int row = e >> 2, c0 = (e & 3) << 3;
      *(short8*)&As[row][c0] = *(const short8*)&a_bf[(size_t)(m0 + row) * CC + kt + c0];
    }
#pragma unroll
    for (int i = 0; i < 4; i++) {
      int e = tid + i * 256;
      int n = e & 127, kg = e >> 7;
      const float* p = &Wp[(size_t)(kt + kg * 4) * CC + n0 + n];
      float b0 = p[0], b1 = p[CC], b2 = p[2 * CC], b3 = p[3 * CC];
      *(us4*)&Bs[n][kg * 4] = us4{f2bf(b0), f2bf(b1), f2bf(b2), f2bf(b3)};
    }
    __syncthreads();
    short8 af[4], bfr[4];
#pragma unroll
    for (int mf = 0; mf < 4; mf++) af[mf]  = *(const short8*)&As[mh + mf * 16 + ln][qd * 8];
#pragma unroll
    for (int nf = 0; nf < 4; nf++) bfr[nf] = *(const short8*)&Bs[nh + nf * 16 + ln][qd * 8];
#pragma unroll
    for (int mf = 0; mf < 4; mf++)
#pragma unroll
      for (int nf = 0; nf < 4; nf++)
        acc[mf][nf] = __builtin_amdgcn_mfma_f32_16x16x32_bf16(af[mf], bfr[nf], acc[mf][nf], 0, 0, 0);
  }

#pragma unroll
  for (int mf = 0; mf < 4; mf++)
#pragma unroll
    for (int nf = 0; nf < 4; nf++) {
      int gn = n0 + nh + nf * 16 + ln;
      float bias = bp[gn];
#pragma unroll
      for (int r = 0; r < 4; r++) {
        int gm = m0 + mh + mf * 16 + qd * 4 + r;
        out[(size_t)gm * CC + gn] = acc[mf][nf][r] + bias;
      }
    }
}

// ---------------------------------------------------------------------------
// Workspace map (48 MB total):
//   [ 0,  8M)  q_ws  bf16 (B,H,T,D)
//   [ 8, 24M)  k_ws  bf16 (B,H,TK,D)
//   [24, 40M)  v_ws  bf16 (B,H,TK,D)
//   [40, 48M)  wv_ws bf16 (B*T, C)
// ---------------------------------------------------------------------------
extern "C" void kernel_launch(void* const* d_in, const int* in_sizes, int n_in,
                              void* d_out, int out_size, void* d_ws, size_t ws_size,
                              hipStream_t stream) {
  const float* rel = (const float*)d_in[0];
  const float* x   = (const float*)d_in[1];
  const float* xl  = (const float*)d_in[2];
  const float* Wq  = (const float*)d_in[3];
  const float* Wk  = (const float*)d_in[4];
  const float* Wv  = (const float*)d_in[5];
  const float* Wp  = (const float*)d_in[6];
  const float* bp  = (const float*)d_in[7];
  float* out    = (float*)d_out;
  float* out_xl = out + (size_t)BT * CC;  // new_xl_memory (B,T,2,C)

  char* ws = (char*)d_ws;
  unsigned short* q_ws  = (unsigned short*)(ws);
  unsigned short* k_ws  = (unsigned short*)(ws + (size_t)(8)  * 1024 * 1024);
  unsigned short* v_ws  = (unsigned short*)(ws + (size_t)(24) * 1024 * 1024);
  unsigned short* wv_ws = (unsigned short*)(ws + (size_t)(40) * 1024 * 1024);

  prep_xl_k<<<dim3(4096), dim3(256), 0, stream>>>(xl, k_ws, v_ws);
  gemm_qkv_k<<<dim3(32, 24), dim3(256), 0, stream>>>(x, Wq, Wk, Wv, q_ws, k_ws, v_ws, out_xl);
  attn_k<<<dim3(1024), dim3(256), 0, stream>>>(q_ws, k_ws, v_ws, rel, wv_ws);
  gemm_out_k<<<dim3(32, 8), dim3(256), 0, stream>>>(wv_ws, Wp, bp, out);
}

// Round 3
// 982.403 us; speedup vs baseline: 1.0661x; 1.0103x over previous
//
#include <hip/hip_runtime.h>
#include <hip/hip_bf16.h>

// Problem constants
constexpr int NB  = 2;     // batch
constexpr int TT  = 2048;  // T
constexpr int MEM = 2048;  // M (xl memory length)
constexpr int CC  = 1024;  // C
constexpr int NH  = 16;    // heads
constexpr int HD  = 64;    // head dim
constexpr int TKK = 4096;  // T + M
constexpr int BT  = NB * TT;

typedef __attribute__((ext_vector_type(8))) short short8;
typedef __attribute__((ext_vector_type(4))) float floatx4;

struct __align__(8) us4 { unsigned short x, y, z, w; };

__device__ __forceinline__ unsigned short f2bf(float f) {
  union { float f; unsigned int u; } v; v.f = f;
  return (unsigned short)((v.u + 0x7fffu + ((v.u >> 16) & 1u)) >> 16);
}

// ---------------------------------------------------------------------------
// Kernel 1: xl_memory (B, M, 2, C) fp32 -> k_ws / v_ws bf16 in (B, H, TK, D)
// layout (rows 0..M-1). Rows M..TK-1 are filled by gemm_qkv.
// ---------------------------------------------------------------------------
__global__ __launch_bounds__(256) void prep_xl_k(const float* __restrict__ xl,
    unsigned short* __restrict__ k_ws, unsigned short* __restrict__ v_ws) {
  int idx = blockIdx.x * 256 + threadIdx.x;  // over NB*MEM*CC/4 = 1048576
  int c   = (idx & 255) << 2;                // CC/4 = 256 groups of 4
  int rem = idx >> 8;
  int m   = rem & 2047;
  int b   = rem >> 11;
  size_t src = ((size_t)(b * MEM + m)) * 2 * CC + c;
  float4 kk = *(const float4*)&xl[src];
  float4 vv = *(const float4*)&xl[src + CC];
  int h = c >> 6, d = c & 63;
  size_t dst = ((size_t)((b * NH + h) * TKK) + m) * HD + d;
  *(us4*)&k_ws[dst] = us4{f2bf(kk.x), f2bf(kk.y), f2bf(kk.z), f2bf(kk.w)};
  *(us4*)&v_ws[dst] = us4{f2bf(vv.x), f2bf(vv.y), f2bf(vv.z), f2bf(vv.w)};
}

// ---------------------------------------------------------------------------
// Kernel 2: QKV projection. A = x (4096x1024 fp32), B = [Wq|Wk|Wv].
// 128x128 tile, BK=32, 4 waves each 64x64 (4x4 of 16x16x32 bf16 MFMA).
// As padded to 40 shorts/row (80 B = 20-bank stride): A-frag ds_read_b128 was
// an 8-way bank conflict at 64 B stride, now ~2-way (free).
// ---------------------------------------------------------------------------
__global__ __launch_bounds__(256) void gemm_qkv_k(
    const float* __restrict__ x, const float* __restrict__ Wq,
    const float* __restrict__ Wk, const float* __restrict__ Wv,
    unsigned short* __restrict__ q_ws, unsigned short* __restrict__ k_ws,
    unsigned short* __restrict__ v_ws, float* __restrict__ out_xl) {
  __shared__ unsigned short As[128][40];  // [m][k], pad 32->40
  __shared__ unsigned short Bs[128][40];  // transposed [n][k], pad 8 -> 16B-aligned rows
  const int tid = threadIdx.x;
  const int m0 = blockIdx.x * 128;
  const int nb = blockIdx.y;  // 0..23 over 3072 cols
  const float* __restrict__ Wsrc = (nb < 8) ? Wq : ((nb < 16) ? Wk : Wv);
  const int n0 = (nb & 7) * 128;
  const int wave = tid >> 6, lane = tid & 63;
  const int mh = (wave >> 1) * 64, nh = (wave & 1) * 64;
  const int ln = lane & 15, qd = lane >> 4;
  const floatx4 fzero = {0.f, 0.f, 0.f, 0.f};

  floatx4 acc[4][4];
#pragma unroll
  for (int i = 0; i < 4; i++)
#pragma unroll
    for (int j = 0; j < 4; j++) acc[i][j] = fzero;

  for (int kt = 0; kt < CC; kt += 32) {
    __syncthreads();
    // stage A: 128x32 fp32 -> bf16, coalesced float4
#pragma unroll
    for (int i = 0; i < 4; i++) {
      int e = tid + i * 256;
      int row = e >> 3, kc = (e & 7) << 2;
      float4 a4 = *(const float4*)&x[(size_t)(m0 + row) * CC + kt + kc];
      *(us4*)&As[row][kc] = us4{f2bf(a4.x), f2bf(a4.y), f2bf(a4.z), f2bf(a4.w)};
    }
    // stage B transposed: each thread reads 4 k-rows at one n (coalesced dwords),
    // writes one contiguous b64 to Bs[n][4k..]
#pragma unroll
    for (int i = 0; i < 4; i++) {
      int e = tid + i * 256;
      int n = e & 127, kg = e >> 7;
      const float* p = &Wsrc[(size_t)(kt + kg * 4) * CC + n0 + n];
      float b0 = p[0], b1 = p[CC], b2 = p[2 * CC], b3 = p[3 * CC];
      *(us4*)&Bs[n][kg * 4] = us4{f2bf(b0), f2bf(b1), f2bf(b2), f2bf(b3)};
    }
    __syncthreads();
    short8 af[4], bfr[4];
#pragma unroll
    for (int mf = 0; mf < 4; mf++) af[mf]  = *(const short8*)&As[mh + mf * 16 + ln][qd * 8];
#pragma unroll
    for (int nf = 0; nf < 4; nf++) bfr[nf] = *(const short8*)&Bs[nh + nf * 16 + ln][qd * 8];
#pragma unroll
    for (int mf = 0; mf < 4; mf++)
#pragma unroll
      for (int nf = 0; nf < 4; nf++)
        acc[mf][nf] = __builtin_amdgcn_mfma_f32_16x16x32_bf16(af[mf], bfr[nf], acc[mf][nf], 0, 0, 0);
  }

  const int sel = nb >> 3;  // 0=q 1=k 2=v
#pragma unroll
  for (int mf = 0; mf < 4; mf++) {
#pragma unroll
    for (int nf = 0; nf < 4; nf++) {
      int gn = n0 + nh + nf * 16 + ln;  // 0..1023 within matrix
      int h = gn >> 6, d = gn & 63;
#pragma unroll
      for (int r = 0; r < 4; r++) {
        int gm = m0 + mh + mf * 16 + qd * 4 + r;  // C/D layout: row = quad*4+reg
        int b = gm >> 11, t = gm & 2047;
        float val = acc[mf][nf][r];
        unsigned short bv = f2bf(val);
        if (sel == 0) {
          q_ws[((size_t)((b * NH + h) * TT) + t) * HD + d] = bv;
        } else if (sel == 1) {
          k_ws[((size_t)((b * NH + h) * TKK) + MEM + t) * HD + d] = bv;
          out_xl[(((size_t)(b * TT + t)) * 2 + 0) * CC + gn] = val;
        } else {
          v_ws[((size_t)((b * NH + h) * TKK) + MEM + t) * HD + d] = bv;
          out_xl[(((size_t)(b * TT + t)) * 2 + 1) * CC + gn] = val;
        }
      }
    }
  }
}

// ---------------------------------------------------------------------------
// Kernel 3: flash attention. One block per (q-tile of 64 rows, head, batch).
// Batch fastest grid bit (bias L2/L3 pairing); qt descending (long blocks 1st).
// Double-buffered K/V, one barrier/tile, reg-prefetch of K/V/bias (T14).
// NEW this round:
//  - softmax denominator l accumulated as an extra PV MFMA against an all-ones
//    B-frag (same alpha-rescale recurrence as O; ones in all 16 cols -> every
//    lane holds the row sum, no broadcast). Removes the 16 sum-shfls/tile
//    (~50% of ds_swizzle traffic) + the per-frag sum VALU.
//  - s_setprio(1) around MFMA clusters (3 independent blocks/CU give the CU
//    scheduler role diversity; m191-style +4-7%).
// ---------------------------------------------------------------------------
__global__ __launch_bounds__(256) void attn_k(
    const unsigned short* __restrict__ q_ws, const unsigned short* __restrict__ k_ws,
    const unsigned short* __restrict__ v_ws, const float* __restrict__ rel,
    unsigned short* __restrict__ wv_ws) {
  __shared__ unsigned short Ks[2][64][72];  // natural [kcol][dim], pad 8
  __shared__ unsigned short Vs[2][64][72];  // transposed [dim][krow], XOR-swizzled 8-elem groups, pad 8
  __shared__ unsigned short Ps[4][16][72];  // per-wave P scratch, same swizzle, pad 8
  const int idx = blockIdx.x;       // 0..1023
  const int qt = 31 - (idx >> 5);   // descending work order
  const int h  = (idx >> 1) & 15;
  const int b  = idx & 1;
  const int tid = threadIdx.x;
  const int wave = tid >> 6, lane = tid & 63;
  const int ln = lane & 15, qd = lane >> 4;
  const int q0 = qt * 64;
  const int qrow_w = q0 + wave * 16;
  const floatx4 fzero = {0.f, 0.f, 0.f, 0.f};

  // staging roles
  const int kr0 = tid >> 3;            // 0..31 (second b128 covers +32)
  const int kc0 = (tid & 7) << 3;      // 0..56
  const int vd  = tid & 63;            // V column (d)
  const int vkg = tid >> 6;            // V k-group of 16
  const size_t khbase = (size_t)((b * NH + h) * TKK);

  // all-ones bf16 B-frag for the l-accumulating MFMA
  short8 onesf;
#pragma unroll
  for (int j = 0; j < 8; j++) onesf[j] = (short)0x3F80;

  // Q A-frags: lane holds Q[m=ln][qd*8..+8 (+32*ks)]
  short8 qf[2];
#pragma unroll
  for (int ks = 0; ks < 2; ks++)
    qf[ks] = *(const short8*)&q_ws[((size_t)((b * NH + h) * TT) + qrow_w + ln) * HD + ks * 32 + qd * 8];

  // bias row bases (4 rows per thread)
  const float* biasrow[4];
#pragma unroll
  for (int r = 0; r < 4; r++)
    biasrow[r] = &rel[((size_t)(h * TT) + qrow_w + qd * 4 + r) * TKK + ln];

  floatx4 of[4];
  floatx4 lac;            // row-sum accumulator (every lane holds its row's l)
  float mrow[4];
#pragma unroll
  for (int nf = 0; nf < 4; nf++) of[nf] = fzero;
  lac = fzero;
#pragma unroll
  for (int r = 0; r < 4; r++) mrow[r] = -1e30f;

  const int ntiles = qt + 33;  // valid k-tiles: cols <= q0+63+2048

  // ---- prologue: stage tile 0 into buffer 0 ----
  float bcur[16];
  {
    short8 k0 = *(const short8*)&k_ws[(khbase + kr0) * HD + kc0];
    short8 k1 = *(const short8*)&k_ws[(khbase + kr0 + 32) * HD + kc0];
    ushort2 vv[8];
    const unsigned short* vp = &v_ws[(khbase + vkg * 16) * HD + vd];
#pragma unroll
    for (int j = 0; j < 8; j++) {
      vv[j].x = vp[(2 * j) * HD];
      vv[j].y = vp[(2 * j + 1) * HD];
    }
#pragma unroll
    for (int nf = 0; nf < 4; nf++)
#pragma unroll
      for (int r = 0; r < 4; r++)
        bcur[nf * 4 + r] = biasrow[r][nf * 16];
    *(short8*)&Ks[0][kr0][kc0] = k0;
    *(short8*)&Ks[0][kr0 + 32][kc0] = k1;
#pragma unroll
    for (int jj = 0; jj < 2; jj++) {
      int slot = ((vkg * 2 + jj) ^ (vd & 7) ^ (vd >> 3)) & 7;
      short8 w;
#pragma unroll
      for (int t = 0; t < 4; t++) {
        w[2 * t]     = (short)vv[jj * 4 + t].x;
        w[2 * t + 1] = (short)vv[jj * 4 + t].y;
      }
      *(short8*)&Vs[0][vd][slot << 3] = w;
    }
  }
  __syncthreads();

  int c = 0;
  for (int kt = 0; kt < ntiles; kt++) {
    const int kbase = kt * 64;
    const bool more = (kt + 1 < ntiles);

    // ---- issue prefetch for tile kt+1 (loads only; writes after compute) ----
    short8 nk0, nk1;
    ushort2 nvv[8];
    float bnx[16];
    if (more) {
      const size_t rb = khbase + kbase + 64;
      nk0 = *(const short8*)&k_ws[(rb + kr0) * HD + kc0];
      nk1 = *(const short8*)&k_ws[(rb + kr0 + 32) * HD + kc0];
      const unsigned short* vp = &v_ws[(rb + vkg * 16) * HD + vd];
#pragma unroll
      for (int j = 0; j < 8; j++) {
        nvv[j].x = vp[(2 * j) * HD];
        nvv[j].y = vp[(2 * j + 1) * HD];
      }
#pragma unroll
      for (int nf = 0; nf < 4; nf++)
#pragma unroll
        for (int r = 0; r < 4; r++)
          bnx[nf * 4 + r] = biasrow[r][kbase + 64 + nf * 16];
    }

    // ---- compute on buffer c ----
    floatx4 sacc[4];
#pragma unroll
    for (int nf = 0; nf < 4; nf++) sacc[nf] = fzero;
    __builtin_amdgcn_s_setprio(1);
#pragma unroll
    for (int ks = 0; ks < 2; ks++)
#pragma unroll
      for (int nf = 0; nf < 4; nf++) {
        short8 kf = *(const short8*)&Ks[c][nf * 16 + ln][ks * 32 + qd * 8];
        sacc[nf] = __builtin_amdgcn_mfma_f32_16x16x32_bf16(qf[ks], kf, sacc[nf], 0, 0, 0);
      }
    __builtin_amdgcn_s_setprio(0);

    float sv[4][4];
#pragma unroll
    for (int nf = 0; nf < 4; nf++)
#pragma unroll
      for (int r = 0; r < 4; r++)
        sv[nf][r] = (sacc[nf][r] + bcur[nf * 4 + r]) * 0.125f;  // (qk + rel) * d^-0.5
    if (kt == ntiles - 1) {
#pragma unroll
      for (int nf = 0; nf < 4; nf++)
#pragma unroll
        for (int r = 0; r < 4; r++) {
          int kcol = kbase + nf * 16 + ln;
          int qrow = qrow_w + qd * 4 + r;
          if (kcol > qrow + MEM) sv[nf][r] = -1e30f;
        }
    }

    // online softmax: only the MAX needs a cross-lane reduce now
#pragma unroll
    for (int r = 0; r < 4; r++) {
      float mx = fmaxf(fmaxf(sv[0][r], sv[1][r]), fmaxf(sv[2][r], sv[3][r]));
#pragma unroll
      for (int off = 8; off >= 1; off >>= 1)
        mx = fmaxf(mx, __shfl_xor(mx, off, 64));
      float mnew = fmaxf(mrow[r], mx);
      float alpha = __expf(mrow[r] - mnew);
      mrow[r] = mnew;
#pragma unroll
      for (int nf = 0; nf < 4; nf++) sv[nf][r] = __expf(sv[nf][r] - mnew);
      lac[r] *= alpha;
#pragma unroll
      for (int nf = 0; nf < 4; nf++) of[nf][r] *= alpha;
    }

    // P: C-layout -> LDS (swizzled) -> A-layout (per-wave private, no barrier)
#pragma unroll
    for (int nf = 0; nf < 4; nf++)
#pragma unroll
      for (int r = 0; r < 4; r++) {
        int row = qd * 4 + r;
        int col = nf * 16 + ln;
        int slot = ((col >> 3) ^ (row & 7) ^ (row >> 3)) & 7;
        Ps[wave][row][(slot << 3) | (col & 7)] = f2bf(sv[nf][r]);
      }

    __builtin_amdgcn_s_setprio(1);
#pragma unroll
    for (int ks = 0; ks < 2; ks++) {
      int g = qd + 4 * ks;
      int pslot = (g ^ (ln & 7) ^ (ln >> 3)) & 7;
      short8 pf = *(const short8*)&Ps[wave][ln][pslot << 3];
#pragma unroll
      for (int nf = 0; nf < 4; nf++) {
        int dd = nf * 16 + ln;
        int vslot = (g ^ (dd & 7) ^ (dd >> 3)) & 7;
        short8 vf = *(const short8*)&Vs[c][dd][vslot << 3];
        of[nf] = __builtin_amdgcn_mfma_f32_16x16x32_bf16(pf, vf, of[nf], 0, 0, 0);
      }
      // l-accumulation: P @ ones -> row sums replicated across all 16 cols
      lac = __builtin_amdgcn_mfma_f32_16x16x32_bf16(pf, onesf, lac, 0, 0, 0);
    }
    __builtin_amdgcn_s_setprio(0);

    // ---- write prefetched tile into the other buffer, then single barrier ----
    if (more) {
      *(short8*)&Ks[c ^ 1][kr0][kc0] = nk0;
      *(short8*)&Ks[c ^ 1][kr0 + 32][kc0] = nk1;
#pragma unroll
      for (int jj = 0; jj < 2; jj++) {
        int slot = ((vkg * 2 + jj) ^ (vd & 7) ^ (vd >> 3)) & 7;
        short8 w;
#pragma unroll
        for (int t = 0; t < 4; t++) {
          w[2 * t]     = (short)nvv[jj * 4 + t].x;
          w[2 * t + 1] = (short)nvv[jj * 4 + t].y;
        }
        *(short8*)&Vs[c ^ 1][vd][slot << 3] = w;
      }
#pragma unroll
      for (int i = 0; i < 16; i++) bcur[i] = bnx[i];
    }
    __syncthreads();
    c ^= 1;
  }

  // normalize + store wv (bf16) in (B*T, C) for the out-proj GEMM
  {
    float inv[4];
#pragma unroll
    for (int r = 0; r < 4; r++) inv[r] = 1.f / lac[r];
#pragma unroll
    for (int nf = 0; nf < 4; nf++)
#pragma unroll
      for (int r = 0; r < 4; r++)
        wv_ws[((size_t)(b * TT) + qrow_w + qd * 4 + r) * CC + h * 64 + nf * 16 + ln] =
            f2bf(of[nf][r] * inv[r]);
  }
}

// ---------------------------------------------------------------------------
// Kernel 4: out = wv @ Wp + bp   (A bf16 ws, B fp32 -> bf16, out fp32)
// As padded 32->40 (same 8-way conflict fix as gemm_qkv).
// ---------------------------------------------------------------------------
__global__ __launch_bounds__(256) void gemm_out_k(
    const unsigned short* __restrict__ a_bf, const float* __restrict__ Wp,
    const float* __restrict__ bp, float* __restrict__ out) {
  __shared__ unsigned short As[128][40];
  __shared__ unsigned short Bs[128][40];
  const int tid = threadIdx.x;
  const int m0 = blockIdx.x * 128;
  const int n0 = blockIdx.y * 128;
  const int wave = tid >> 6, lane = tid & 63;
  const int mh = (wave >> 1) * 64, nh = (wave & 1) * 64;
  const int ln = lane & 15, qd = lane >> 4;
  const floatx4 fzero = {0.f, 0.f, 0.f, 0.f};

  floatx4 acc[4][4];
#pragma unroll
  for (int i = 0; i < 4; i++)
#pragma unroll
    for (int j = 0; j < 4; j++) acc[i][j] = fzero;

  for (int kt = 0; kt < CC; kt += 32) {
    __syncthreads();
#pragma unroll
    for (int i = 0; i < 2; i++) {  // A already bf16: b128 copies
      int e = tid + i * 256;
      int row = e >> 2, c0 = (e & 3) << 3;
      *(short8*)&As[row][c0] = *(const short8*)&a_bf[(size_t)(m0 + row) * CC + kt + c0];
    }
#pragma unroll
    for (int i = 0; i < 4; i++) {
      int e = tid + i * 256;
      int n = e & 127, kg = e >> 7;
      const float* p = &Wp[(size_t)(kt + kg * 4) * CC + n0 + n];
      float b0 = p[0], b1 = p[CC], b2 = p[2 * CC], b3 = p[3 * CC];
      *(us4*)&Bs[n][kg * 4] = us4{f2bf(b0), f2bf(b1), f2bf(b2), f2bf(b3)};
    }
    __syncthreads();
    short8 af[4], bfr[4];
#pragma unroll
    for (int mf = 0; mf < 4; mf++) af[mf]  = *(const short8*)&As[mh + mf * 16 + ln][qd * 8];
#pragma unroll
    for (int nf = 0; nf < 4; nf++) bfr[nf] = *(const short8*)&Bs[nh + nf * 16 + ln][qd * 8];
#pragma unroll
    for (int mf = 0; mf < 4; mf++)
#pragma unroll
      for (int nf = 0; nf < 4; nf++)
        acc[mf][nf] = __builtin_amdgcn_mfma_f32_16x16x32_bf16(af[mf], bfr[nf], acc[mf][nf], 0, 0, 0);
  }

#pragma unroll
  for (int mf = 0; mf < 4; mf++)
#pragma unroll
    for (int nf = 0; nf < 4; nf++) {
      int gn = n0 + nh + nf * 16 + ln;
      float bias = bp[gn];
#pragma unroll
      for (int r = 0; r < 4; r++) {
        int gm = m0 + mh + mf * 16 + qd * 4 + r;
        out[(size_t)gm * CC + gn] = acc[mf][nf][r] + bias;
      }
    }
}

// ---------------------------------------------------------------------------
// Workspace map (48 MB total):
//   [ 0,  8M)  q_ws  bf16 (B,H,T,D)
//   [ 8, 24M)  k_ws  bf16 (B,H,TK,D)
//   [24, 40M)  v_ws  bf16 (B,H,TK,D)
//   [40, 48M)  wv_ws bf16 (B*T, C)
// ---------------------------------------------------------------------------
extern "C" void kernel_launch(void* const* d_in, const int* in_sizes, int n_in,
                              void* d_out, int out_size, void* d_ws, size_t ws_size,
                              hipStream_t stream) {
  const float* rel = (const float*)d_in[0];
  const float* x   = (const float*)d_in[1];
  const float* xl  = (const float*)d_in[2];
  const float* Wq  = (const float*)d_in[3];
  const float* Wk  = (const float*)d_in[4];
  const float* Wv  = (const float*)d_in[5];
  const float* Wp  = (const float*)d_in[6];
  const float* bp  = (const float*)d_in[7];
  float* out    = (float*)d_out;
  float* out_xl = out + (size_t)BT * CC;  // new_xl_memory (B,T,2,C)

  char* ws = (char*)d_ws;
  unsigned short* q_ws  = (unsigned short*)(ws);
  unsigned short* k_ws  = (unsigned short*)(ws + (size_t)(8)  * 1024 * 1024);
  unsigned short* v_ws  = (unsigned short*)(ws + (size_t)(24) * 1024 * 1024);
  unsigned short* wv_ws = (unsigned short*)(ws + (size_t)(40) * 1024 * 1024);

  prep_xl_k<<<dim3(4096), dim3(256), 0, stream>>>(xl, k_ws, v_ws);
  gemm_qkv_k<<<dim3(32, 24), dim3(256), 0, stream>>>(x, Wq, Wk, Wv, q_ws, k_ws, v_ws, out_xl);
  attn_k<<<dim3(1024), dim3(256), 0, stream>>>(q_ws, k_ws, v_ws, rel, wv_ws);
  gemm_out_k<<<dim3(32, 8), dim3(256), 0, stream>>>(wv_ws, Wp, bp, out);
}